// Round 6
// baseline (1909.501 us; speedup 1.0000x reference)
//
#include <hip/hip_runtime.h>
#include <float.h>
#include <stdint.h>

#define QB        8
#define NTHREADS  512
#define LQ        2048
#define NDIM      64
#define KSEL      128
#define LDS_BYTES 75776
#define WS_NEEDED (2u * 8388608u * 2u)   // Khi + Klo, bf16 each: 33.6 MB

typedef __attribute__((ext_vector_type(8))) short  s8v;   // 8 bf16 (4 VGPRs)
typedef __attribute__((ext_vector_type(4))) float  f32x4; // MFMA C/D

// Order-preserving map fp32 -> uint32 (monotone increasing)
__device__ __forceinline__ unsigned ordf(float f) {
  unsigned u = __float_as_uint(f);
  return (u & 0x80000000u) ? ~u : (u | 0x80000000u);
}
__device__ __forceinline__ float unordf(unsigned u) {
  unsigned x = (u & 0x80000000u) ? (u & 0x7FFFFFFFu) : ~u;
  return __uint_as_float(x);
}
__device__ __forceinline__ unsigned short f2bf(float f) {  // RNE, no NaN in data
  unsigned u = __float_as_uint(f);
  return (unsigned short)((u + 0x7FFFu + ((u >> 16) & 1u)) >> 16);
}
__device__ __forceinline__ float bf2f(unsigned short h) {
  return __uint_as_float(((unsigned)h) << 16);
}

// ---- prepass: K fp32 -> (Khi, Klo) bf16 split, one-time ----
extern "C" __global__ void __launch_bounds__(256)
convert_k(const float4* __restrict__ K4, ushort4* __restrict__ Khi,
          ushort4* __restrict__ Klo) {
  const int idx = blockIdx.x * 256 + threadIdx.x;   // 0 .. 2097151
  const float4 f = K4[idx];
  ushort4 h, l;
  h.x = f2bf(f.x); l.x = f2bf(f.x - bf2f(h.x));
  h.y = f2bf(f.y); l.y = f2bf(f.y - bf2f(h.y));
  h.z = f2bf(f.z); l.z = f2bf(f.z - bf2f(h.z));
  h.w = f2bf(f.w); l.w = f2bf(f.w - bf2f(h.w));
  Khi[idx] = h;
  Klo[idx] = l;
}

extern "C" __global__ void __launch_bounds__(NTHREADS, 4)
topk_attn_mfma(const float* __restrict__ Qg_, const float* __restrict__ Vg_,
               const unsigned short* __restrict__ Khi_,
               const unsigned short* __restrict__ Klo_,
               float* __restrict__ Out) {
  extern __shared__ char lds[];
  float*          s_phys = (float*)(lds);                    // [QB][LQ] 65536 B
  unsigned short* qs_hi  = (unsigned short*)(lds + 65536);   // [QB][NDIM] 1024 B
  unsigned short* qs_lo  = (unsigned short*)(lds + 66560);   // 1024 B
  int*            lists  = (int*)(lds + 67584);              // [QB][KSEL] 4096 B
  float*          wlist  = (float*)(lds + 71680);            // 4096 B

  // ---- XCD-aware swizzle: 32 consecutive blocks per XCD share one (b,h) ----
  const int id  = blockIdx.x;
  const int xcd = id & 7;
  const int w   = id >> 3;
  const int bh  = w >> 5;                   // 0..63
  const int qb8 = ((w & 31) << 3) + xcd;    // 0..255, bijective

  const int q0   = qb8 * QB;
  const int tid  = threadIdx.x;
  const int lane = tid & 63;
  const int wid  = tid >> 6;
  const int m16  = lane & 15;
  const int quad = lane >> 4;

  const float* Qg  = Qg_ + ((size_t)(bh * LQ + q0)) * NDIM;
  const float* Vg  = Vg_ + ((size_t)bh) * LQ * NDIM;
  const unsigned short* Khi = Khi_ + ((size_t)bh) * LQ * NDIM;
  const unsigned short* Klo = Klo_ + ((size_t)bh) * LQ * NDIM;

  // ---- stage Q block, bf16-split, into LDS (512 threads == QB*NDIM elems) ----
  {
    const float f = Qg[tid];
    const unsigned short h = f2bf(f);
    qs_hi[tid] = h;
    qs_lo[tid] = f2bf(f - bf2f(h));
  }
  __syncthreads();

  // ---- A fragments (Q): rows m16<QB real, else zero ----
  s8v Ah0 = {0,0,0,0,0,0,0,0}, Ah1 = Ah0, Al0 = Ah0, Al1 = Ah0;
  if (m16 < QB) {
    const unsigned short* qh = qs_hi + m16 * NDIM + quad * 8;
    const unsigned short* ql = qs_lo + m16 * NDIM + quad * 8;
    Ah0 = *(const s8v*)qh;
    Ah1 = *(const s8v*)(qh + 32);
    Al0 = *(const s8v*)ql;
    Al1 = *(const s8v*)(ql + 32);
  }

  // tile bounds: compute tiles have a valid key (jt <= clim);
  // mask tiles up to the selection-read boundary (jt < wlim) get -FLT_MAX.
  const int clim = (q0 + QB - 1) >> 4;
  const int wlim = (((q0 + QB - 1) >> 8) + 1) << 4;

  int t = 0;
#pragma unroll 2
  for (; t < 16; ++t) {
    const int jt = wid + 8 * t;
    if (jt > clim) break;
    const int jc = (jt << 4) + m16;          // this lane's key row/column
    const unsigned short* kh = Khi + (size_t)jc * NDIM + quad * 8;
    const unsigned short* kl = Klo + (size_t)jc * NDIM + quad * 8;
    const s8v Bh0 = *(const s8v*)kh;
    const s8v Bh1 = *(const s8v*)(kh + 32);
    const s8v Bl0 = *(const s8v*)kl;
    const s8v Bl1 = *(const s8v*)(kl + 32);
    f32x4 c = {0.f, 0.f, 0.f, 0.f};
    c = __builtin_amdgcn_mfma_f32_16x16x32_bf16(Ah0, Bh0, c, 0, 0, 0);
    c = __builtin_amdgcn_mfma_f32_16x16x32_bf16(Ah1, Bh1, c, 0, 0, 0);
    c = __builtin_amdgcn_mfma_f32_16x16x32_bf16(Ah0, Bl0, c, 0, 0, 0);
    c = __builtin_amdgcn_mfma_f32_16x16x32_bf16(Ah1, Bl1, c, 0, 0, 0);
    c = __builtin_amdgcn_mfma_f32_16x16x32_bf16(Al0, Bh0, c, 0, 0, 0);
    c = __builtin_amdgcn_mfma_f32_16x16x32_bf16(Al1, Bh1, c, 0, 0, 0);
    // C/D: col=lane&15 (key), row=quad*4+reg (query). Only rows<QB exist.
    if (quad < 2) {
#pragma unroll
      for (int reg = 0; reg < 4; ++reg) {
        const int r = quad * 4 + reg;
        s_phys[r * LQ + jc] = (jc <= q0 + r) ? c[reg] : -FLT_MAX;
      }
    }
  }
  for (; t < 16; ++t) {
    const int jt = wid + 8 * t;
    if (jt >= wlim) break;
    const int jc = (jt << 4) + m16;
    if (quad < 2) {
#pragma unroll
      for (int reg = 0; reg < 4; ++reg)
        s_phys[(quad * 4 + reg) * LQ + jc] = -FLT_MAX;
    }
  }
  __syncthreads();

  // ---- per-wave: one query; register top-128 + softmax + PV gather ----
  const float C = 0.18033688011112042f; // 0.125 * log2(e)
  const unsigned long long ltmask = (1ull << lane) - 1ull;
  const int qi = wid;
  const int q = q0 + qi;
  const float* srow = s_phys + qi * LQ;
  const float4* srow4 = (const float4*)srow;
  const int g8 = q >> 8;   // causal bound: groups i8 <= g8 contain valid keys

  // load scores (conflict-free b128) as ordered uints; u[4*i8+c] <-> j=i8*256+lane*4+c
  unsigned u[32];
#pragma unroll
  for (int i8 = 0; i8 < 8; ++i8) {
    if (i8 <= g8) {
      const float4 v = srow4[lane + (i8 << 6)];
      u[4 * i8 + 0] = ordf(v.x);
      u[4 * i8 + 1] = ordf(v.y);
      u[4 * i8 + 2] = ordf(v.z);
      u[4 * i8 + 3] = ordf(v.w);
    } else {
      u[4 * i8 + 0] = u[4 * i8 + 1] = u[4 * i8 + 2] = u[4 * i8 + 3] = 0u;
    }
  }

  // exact 128th-largest: bitwise radix descent, ballot counting, causal-bounded
  unsigned p = 0;
  int k = KSEL;
#pragma unroll 1
  for (int b = 31; b >= 0; --b) {
    const unsigned T = p | (1u << b);
    int cnt = 0;
#pragma unroll
    for (int i8 = 0; i8 < 8; ++i8) {
      if (i8 <= g8) {
        cnt += (int)__popcll(__ballot(u[4 * i8 + 0] >= T));
        cnt += (int)__popcll(__ballot(u[4 * i8 + 1] >= T));
        cnt += (int)__popcll(__ballot(u[4 * i8 + 2] >= T));
        cnt += (int)__popcll(__ballot(u[4 * i8 + 3] >= T));
      }
    }
    if (cnt >= KSEL) p = T;
    else             k = KSEL - cnt;
  }
  const unsigned tu = p;
  const int krem = k;
  const float wt = exp2f(unordf(tu) * C);  // exactly 0 for masked threshold

  // ---- collect via ballot-prefix positions (no atomics) ----
  float zacc = 0.f;
  int myeq = 0;
  int base = 0;
#pragma unroll
  for (int i8 = 0; i8 < 8; ++i8) {
    if (i8 > g8) break;
#pragma unroll
    for (int c4 = 0; c4 < 4; ++c4) {
      const unsigned ui = u[4 * i8 + c4];
      const unsigned long long b = __ballot(ui > tu);
      if (ui > tu) {
        const int pos = base + (int)__popcll(b & ltmask);
        const int j = i8 * 256 + (lane << 2) + c4;
        const float wv = exp2f(unordf(ui) * C);
        lists[qi * KSEL + pos] = j;
        wlist[qi * KSEL + pos] = wv;
        zacc += wv;
      }
      base += (int)__popcll(b);
      myeq += (ui == tu) ? 1 : 0;
    }
  }
  int n = base;                    // = KSEL - krem (or q+1 when q < KSEL-1)
  if (wt > 0.f) {
    int te = myeq;
#pragma unroll
    for (int off = 1; off < 64; off <<= 1) te += __shfl_xor(te, off, 64);
    if (te == krem) {
#pragma unroll
      for (int i8 = 0; i8 < 8; ++i8) {
        if (i8 > g8) break;
#pragma unroll
        for (int c4 = 0; c4 < 4; ++c4) {
          const unsigned ui = u[4 * i8 + c4];
          const unsigned long long b = __ballot(ui == tu);
          if (ui == tu) {
            const int pos = base + (int)__popcll(b & ltmask);
            const int j = i8 * 256 + (lane << 2) + c4;
            lists[qi * KSEL + pos] = j;
            wlist[qi * KSEL + pos] = wt;
            zacc += wt;
          }
          base += (int)__popcll(b);
        }
      }
      n = base;
    } else {
      // rare: more ties than slots -> take smallest indices (reference order);
      // bound scan to the written/valid column range
      if (lane == 0) {
        const int jmax = (g8 + 1) << 8;
        int taken = 0, pos = base;
        for (int j = 0; j < jmax && taken < krem; ++j) {
          if (ordf(srow[j]) == tu) {
            lists[qi * KSEL + pos] = j;
            wlist[qi * KSEL + pos] = wt;
            pos++; taken++;
          }
        }
        zacc += wt * (float)krem;
      }
      n = KSEL;
    }
  }
  float Z = zacc;
#pragma unroll
  for (int off = 1; off < 64; off <<= 1) Z += __shfl_xor(Z, off, 64);
  __threadfence_block();

  // ---- PV gather: lane = output dim; 16 loads in flight per iter ----
  float accv = 0.f;
  int i = 0;
  for (; i + 16 <= n; i += 16) {
    int4   jv[4];
    float4 wv[4];
#pragma unroll
    for (int g = 0; g < 4; ++g) {
      jv[g] = *(const int4*)  &lists[qi * KSEL + i + 4 * g];
      wv[g] = *(const float4*)&wlist[qi * KSEL + i + 4 * g];
    }
    float v[16];
#pragma unroll
    for (int g = 0; g < 4; ++g) {
      v[4 * g + 0] = Vg[(size_t)jv[g].x * NDIM + lane];
      v[4 * g + 1] = Vg[(size_t)jv[g].y * NDIM + lane];
      v[4 * g + 2] = Vg[(size_t)jv[g].z * NDIM + lane];
      v[4 * g + 3] = Vg[(size_t)jv[g].w * NDIM + lane];
    }
#pragma unroll
    for (int g = 0; g < 4; ++g)
      accv += wv[g].x * v[4 * g + 0] + wv[g].y * v[4 * g + 1] +
              wv[g].z * v[4 * g + 2] + wv[g].w * v[4 * g + 3];
  }
  for (; i < n; ++i) {
    const int j = lists[qi * KSEL + i];
    accv += wlist[qi * KSEL + i] * Vg[(size_t)j * NDIM + lane];
  }
  Out[((size_t)(bh * LQ + q)) * NDIM + lane] = accv / Z;
}

// ================= fallback (round-4 kernel, used if ws too small) =========
#define FB_QB        8
#define FB_LDS_BYTES 73760

extern "C" __global__ void __launch_bounds__(NTHREADS, 4)
topk_attn_fb(const float* __restrict__ Qg_, const float* __restrict__ Kg_,
             const float* __restrict__ Vg_, float* __restrict__ Out) {
  extern __shared__ char lds[];
  float* s_phys = (float*)(lds);
  int*   lists  = (int*)(lds + 65536);
  float* wlist  = (float*)(lds + 69632);
  float* qs     = (float*)(lds + 65536);

  const int id  = blockIdx.x;
  const int xcd = id & 7;
  const int w   = id >> 3;
  const int bh  = w >> 5;
  const int qb  = ((w & 31) << 3) + xcd;

  const int q0   = qb * FB_QB;
  const int tid  = threadIdx.x;
  const int lane = tid & 63;
  const int wid  = tid >> 6;

  const float* Qg = Qg_ + ((size_t)(bh * LQ + q0)) * NDIM;
  const float* Kg = Kg_ + ((size_t)bh) * LQ * NDIM;
  const float* Vg = Vg_ + ((size_t)bh) * LQ * NDIM;

  if (tid < FB_QB * NDIM / 4) ((float4*)qs)[tid] = ((const float4*)Qg)[tid];
  __syncthreads();

  const int tq   = tid >> 8;
  const int tk   = tid & 255;
  const int j0   = tk << 3;
  const int qmax = q0 + FB_QB - 1;
  const bool active = (j0 <= qmax);

  float acc[4][8];
#pragma unroll
  for (int i = 0; i < 4; ++i)
#pragma unroll
    for (int j = 0; j < 8; ++j) acc[i][j] = 0.f;

  if (active) {
    const float4* K4  = (const float4*)(Kg + (size_t)j0 * NDIM);
    const float4* qs4 = (const float4*)(qs + tq * 4 * NDIM);
#pragma unroll 1
    for (int d4 = 0; d4 < 16; ++d4) {
      float4 qv[4];
#pragma unroll
      for (int i = 0; i < 4; ++i) qv[i] = qs4[i * 16 + d4];
#pragma unroll
      for (int g = 0; g < 4; ++g) {
        const float4 k0 = K4[(2 * g + 0) * 16 + d4];
        const float4 k1 = K4[(2 * g + 1) * 16 + d4];
#pragma unroll
        for (int i = 0; i < 4; ++i) {
          acc[i][2 * g + 0] += qv[i].x * k0.x + qv[i].y * k0.y +
                               qv[i].z * k0.z + qv[i].w * k0.w;
          acc[i][2 * g + 1] += qv[i].x * k1.x + qv[i].y * k1.y +
                               qv[i].z * k1.z + qv[i].w * k1.w;
        }
      }
    }
  }
  __syncthreads();

#pragma unroll
  for (int i = 0; i < 4; ++i) {
    const int q = q0 + tq * 4 + i;
    float4* srow4 = (float4*)(s_phys + (tq * 4 + i) * LQ);
    float4 lo, hi;
    lo.x = (j0 + 0 <= q) ? acc[i][0] : -FLT_MAX;
    lo.y = (j0 + 1 <= q) ? acc[i][1] : -FLT_MAX;
    lo.z = (j0 + 2 <= q) ? acc[i][2] : -FLT_MAX;
    lo.w = (j0 + 3 <= q) ? acc[i][3] : -FLT_MAX;
    hi.x = (j0 + 4 <= q) ? acc[i][4] : -FLT_MAX;
    hi.y = (j0 + 5 <= q) ? acc[i][5] : -FLT_MAX;
    hi.z = (j0 + 6 <= q) ? acc[i][6] : -FLT_MAX;
    hi.w = (j0 + 7 <= q) ? acc[i][7] : -FLT_MAX;
    srow4[tk * 2 + 0] = lo;
    srow4[tk * 2 + 1] = hi;
  }
  __syncthreads();

  const float C = 0.18033688011112042f;
  const int qi = wid;
  const int q = q0 + qi;
  const float* srow = s_phys + qi * LQ;
  const float4* srow4 = (const float4*)srow;

  unsigned u[32];
#pragma unroll
  for (int i = 0; i < 8; ++i) {
    const float4 v = srow4[lane + (i << 6)];
    u[4 * i + 0] = ordf(v.x);
    u[4 * i + 1] = ordf(v.y);
    u[4 * i + 2] = ordf(v.z);
    u[4 * i + 3] = ordf(v.w);
  }

  unsigned p = 0;
  int k = KSEL;
#pragma unroll 1
  for (int b = 31; b >= 0; --b) {
    const unsigned T = p | (1u << b);
    int cnt = 0;
#pragma unroll
    for (int i = 0; i < 32; ++i)
      cnt += (int)__popcll(__ballot(u[i] >= T));
    if (cnt >= KSEL) p = T;
    else             k = KSEL - cnt;
  }
  const unsigned tu = p;
  const int krem = k;
  const float wt = exp2f(unordf(tu) * C);

  const unsigned long long ltmask = (1ull << lane) - 1ull;
  float zacc = 0.f;
  int myeq = 0;
  int base = 0;
#pragma unroll
  for (int i = 0; i < 32; ++i) {
    const unsigned ui = u[i];
    const unsigned long long b = __ballot(ui > tu);
    if (ui > tu) {
      const int pos = base + (int)__popcll(b & ltmask);
      const int j = ((i >> 2) << 8) + (lane << 2) + (i & 3);
      const float wv = exp2f(unordf(ui) * C);
      lists[qi * KSEL + pos] = j;
      wlist[qi * KSEL + pos] = wv;
      zacc += wv;
    }
    base += (int)__popcll(b);
    myeq += (ui == tu) ? 1 : 0;
  }
  int n = base;
  if (wt > 0.f) {
    int te = myeq;
#pragma unroll
    for (int off = 1; off < 64; off <<= 1) te += __shfl_xor(te, off, 64);
    if (te == krem) {
#pragma unroll
      for (int i = 0; i < 32; ++i) {
        const unsigned long long b = __ballot(u[i] == tu);
        if (u[i] == tu) {
          const int pos = base + (int)__popcll(b & ltmask);
          const int j = ((i >> 2) << 8) + (lane << 2) + (i & 3);
          lists[qi * KSEL + pos] = j;
          wlist[qi * KSEL + pos] = wt;
          zacc += wt;
        }
        base += (int)__popcll(b);
      }
      n = base;
    } else {
      if (lane == 0) {
        int taken = 0, pos = base;
        for (int j = 0; j < LQ && taken < krem; ++j) {
          if (ordf(srow[j]) == tu) {
            lists[qi * KSEL + pos] = j;
            wlist[qi * KSEL + pos] = wt;
            pos++; taken++;
          }
        }
        zacc += wt * (float)krem;
      }
      n = KSEL;
    }
  }
  float Z = zacc;
#pragma unroll
  for (int off = 1; off < 64; off <<= 1) Z += __shfl_xor(Z, off, 64);
  __threadfence_block();

  float accv = 0.f;
  int i = 0;
  for (; i + 8 <= n; i += 8) {
    const int4   ja = *(const int4*)  &lists[qi * KSEL + i];
    const int4   jb = *(const int4*)  &lists[qi * KSEL + i + 4];
    const float4 wa = *(const float4*)&wlist[qi * KSEL + i];
    const float4 wb = *(const float4*)&wlist[qi * KSEL + i + 4];
    const float v0 = Vg[(size_t)ja.x * NDIM + lane];
    const float v1 = Vg[(size_t)ja.y * NDIM + lane];
    const float v2 = Vg[(size_t)ja.z * NDIM + lane];
    const float v3 = Vg[(size_t)ja.w * NDIM + lane];
    const float v4 = Vg[(size_t)jb.x * NDIM + lane];
    const float v5 = Vg[(size_t)jb.y * NDIM + lane];
    const float v6 = Vg[(size_t)jb.z * NDIM + lane];
    const float v7 = Vg[(size_t)jb.w * NDIM + lane];
    accv += wa.x * v0 + wa.y * v1 + wa.z * v2 + wa.w * v3 +
            wb.x * v4 + wb.y * v5 + wb.z * v6 + wb.w * v7;
  }
  for (; i < n; ++i) {
    const int j = lists[qi * KSEL + i];
    accv += wlist[qi * KSEL + i] * Vg[(size_t)j * NDIM + lane];
  }
  Out[((size_t)(bh * LQ + q)) * NDIM + lane] = accv / Z;
}

extern "C" void kernel_launch(void* const* d_in, const int* in_sizes, int n_in,
                              void* d_out, int out_size, void* d_ws, size_t ws_size,
                              hipStream_t stream) {
  (void)in_sizes; (void)n_in; (void)out_size;
  const float* Q = (const float*)d_in[0];
  const float* K = (const float*)d_in[1];
  const float* V = (const float*)d_in[2];
  float* Out = (float*)d_out;

  if (ws_size >= WS_NEEDED) {
    ushort4* Khi = (ushort4*)d_ws;
    ushort4* Klo = (ushort4*)((char*)d_ws + 8388608u * 2u);
    convert_k<<<dim3(8192), 256, 0, stream>>>((const float4*)K, Khi, Klo);

    (void)hipFuncSetAttribute(reinterpret_cast<const void*>(&topk_attn_mfma),
                              hipFuncAttributeMaxDynamicSharedMemorySize, LDS_BYTES);
    topk_attn_mfma<<<dim3(16384), NTHREADS, LDS_BYTES, stream>>>(
        Q, V, (const unsigned short*)Khi, (const unsigned short*)Klo, Out);
  } else {
    (void)hipFuncSetAttribute(reinterpret_cast<const void*>(&topk_attn_fb),
                              hipFuncAttributeMaxDynamicSharedMemorySize, FB_LDS_BYTES);
    topk_attn_fb<<<dim3(16384), NTHREADS, FB_LDS_BYTES, stream>>>(Q, K, V, Out);
  }
}